// Round 1
// baseline (350.376 us; speedup 1.0000x reference)
//
#include <hip/hip_runtime.h>
#include <math.h>

#define DEG2RAD_F 0.017453292519943295f

__device__ __forceinline__ float sl1(float d) {
    return (d < 1.0f) ? (0.5f * d * d) : (d - 0.5f);
}

__device__ __forceinline__ float remf180(float x) {
    // jnp.remainder(x, 180): result in [0, 180)
    float r = fmodf(x, 180.0f);
    if (r < 0.0f) r += 180.0f;
    return r;
}

__device__ __forceinline__ float softplusf(float x) {
    // log(1 + exp(x)), stable
    if (x > 0.0f) return x + log1pf(expf(-x));
    return log1pf(expf(x));
}

__device__ __forceinline__ void box_corners(float cx, float cy, float w, float h, float t,
                                            float* X, float* Y) {
    float r = t * DEG2RAD_F;
    float c = cosf(r), s = sinf(r);
    const float sx[4] = {-0.5f, 0.5f, 0.5f, -0.5f};
    const float sy[4] = {-0.5f, -0.5f, 0.5f, 0.5f};
#pragma unroll
    for (int i = 0; i < 4; i++) {
        float lx = w * sx[i], ly = h * sy[i];
        X[i] = cx + lx * c - ly * s;
        Y[i] = cy + lx * s + ly * c;
    }
}

// Exact intersection area of two convex CCW quads, replicating the reference:
// inside-tests with -1e-6 tol, 16 segment intersections with 1e-10 den tol,
// centroid over masked pts, invalid pts replaced by first-valid, stable
// ascending sort by atan2 angle, shoelace, zero if n < 3.
__device__ float inter_area(const float* p1x, const float* p1y,
                            const float* p2x, const float* p2y) {
    float px[24], py[24];
    bool mk[24];

    // p1 corners: inside p2?
    for (int i = 0; i < 4; i++) {
        px[i] = p1x[i];
        py[i] = p1y[i];
        bool ins = true;
#pragma unroll
        for (int k = 0; k < 4; k++) {
            int k2 = (k + 1) & 3;
            float ex = p2x[k2] - p2x[k], ey = p2y[k2] - p2y[k];
            float dx = p1x[i] - p2x[k], dy = p1y[i] - p2y[k];
            float cr = ex * dy - ey * dx;
            ins = ins && (cr >= -1e-6f);
        }
        mk[i] = ins;
    }
    // p2 corners: inside p1?
    for (int i = 0; i < 4; i++) {
        px[4 + i] = p2x[i];
        py[4 + i] = p2y[i];
        bool ins = true;
#pragma unroll
        for (int k = 0; k < 4; k++) {
            int k2 = (k + 1) & 3;
            float ex = p1x[k2] - p1x[k], ey = p1y[k2] - p1y[k];
            float dx = p2x[i] - p1x[k], dy = p2y[i] - p1y[k];
            float cr = ex * dy - ey * dx;
            ins = ins && (cr >= -1e-6f);
        }
        mk[4 + i] = ins;
    }
    // edge-edge intersections, index 8 + i*4 + j
    for (int i = 0; i < 4; i++) {
        int i2 = (i + 1) & 3;
        float ax = p1x[i], ay = p1y[i];
        float rx = p1x[i2] - ax, ry = p1y[i2] - ay;
        for (int j = 0; j < 4; j++) {
            int j2 = (j + 1) & 3;
            float cx = p2x[j], cy = p2y[j];
            float ux = p2x[j2] - cx, uy = p2y[j2] - cy;
            float qx = cx - ax, qy = cy - ay;
            float den = rx * uy - ry * ux;
            bool dok = fabsf(den) > 1e-10f;
            float safe = dok ? den : 1.0f;
            float t = (qx * uy - qy * ux) / safe;
            float s = (qx * ry - qy * rx) / safe;
            bool mi = dok && (t >= 0.0f) && (t <= 1.0f) && (s >= 0.0f) && (s <= 1.0f);
            int idx = 8 + i * 4 + j;
            px[idx] = ax + t * rx;
            py[idx] = ay + t * ry;
            mk[idx] = mi;
        }
    }

    int n = 0;
    float sx = 0.0f, sy = 0.0f;
    for (int i = 0; i < 24; i++) {
        if (mk[i]) { n++; sx += px[i]; sy += py[i]; }
    }
    float denom = (float)(n > 1 ? n : 1);
    float cenx = sx / denom, ceny = sy / denom;

    // first valid point (argmax of mask -> first True, else index 0)
    int fi = 0;
    for (int i = 0; i < 24; i++) {
        if (mk[i]) { fi = i; break; }
    }
    float rfx = px[fi], rfy = py[fi];

    float ang[24];
    for (int i = 0; i < 24; i++) {
        if (!mk[i]) { px[i] = rfx; py[i] = rfy; }
        ang[i] = atan2f(py[i] - ceny, px[i] - cenx);
    }

    // stable insertion sort of indices, ascending by angle (matches jnp.argsort)
    int ord[24];
    for (int i = 0; i < 24; i++) ord[i] = i;
    for (int i = 1; i < 24; i++) {
        int oi = ord[i];
        float ai = ang[oi];
        int k = i - 1;
        while (k >= 0 && ang[ord[k]] > ai) {
            ord[k + 1] = ord[k];
            k--;
        }
        ord[k + 1] = oi;
    }

    float area2 = 0.0f;
    for (int i = 0; i < 24; i++) {
        int a0 = ord[i], a1 = ord[(i + 1) % 24];
        area2 += px[a0] * py[a1] - px[a1] * py[a0];
    }
    float area = 0.5f * fabsf(area2);
    return (n >= 3) ? area : 0.0f;
}

// One thread per (b, n, g) pair: gated rotated IoU into ws matrix.
__global__ void iou_kernel(const float* __restrict__ anchors, const float* __restrict__ gtb,
                           float* __restrict__ iou, int N, int Gn, int Bn) {
    int tid = blockIdx.x * blockDim.x + threadIdx.x;
    int total = Bn * N * Gn;
    if (tid >= total) return;
    int g = tid % Gn;
    int rem = tid / Gn;
    int n = rem % N;
    int b = rem / N;

    const float* A = anchors + n * 5;
    const float* Gt = gtb + (b * Gn + g) * 5;
    float ax = A[0], ay = A[1], aw = A[2], ah = A[3], at = A[4];
    float gx = Gt[0], gy = Gt[1], gw = Gt[2], gh = Gt[3], gth = Gt[4];

    float asz = fmaxf(aw, ah), gsz = fmaxf(gw, gh);
    float dx = ax - gx, dy = ay - gy;
    float dist = sqrtf(dx * dx + dy * dy);

    float out = 0.0f;
    if (dist < 0.7f * (asz + gsz)) {
        float p1x[4], p1y[4], p2x[4], p2y[4];
        box_corners(ax, ay, aw, ah, at, p1x, p1y);
        box_corners(gx, gy, gw, gh, gth, p2x, p2y);
        float inter = inter_area(p1x, p1y, p2x, p2y);
        out = inter / (aw * ah + gw * gh - inter + 1e-8f);
    }
    iou[tid] = out;
}

// Per anchor: max over G (first-max tie-break), label + matched gt index.
__global__ void row_kernel(const float* __restrict__ iou, const int* __restrict__ gtl,
                           int* __restrict__ lab, int* __restrict__ mgidx,
                           int N, int Gn, int Bn) {
    int tid = blockIdx.x * blockDim.x + threadIdx.x;
    if (tid >= Bn * N) return;
    int b = tid / N;
    const float* row = iou + (size_t)tid * Gn;
    float mx = row[0];
    int mi = 0;
    for (int g = 1; g < Gn; g++) {
        float v = row[g];
        if (v > mx) { mx = v; mi = g; }
    }
    int l, mg = -1;
    if (mx >= 0.5f) {
        l = gtl[b * Gn + mi] + 1;
        mg = mi;
    } else if (mx < 0.4f) {
        l = 0;
    } else {
        l = -1;
    }
    lab[tid] = l;
    mgidx[tid] = mg;
}

// One block per (g, b): first-argmax over anchors for each gt column.
__global__ void col_kernel(const float* __restrict__ iou, int* __restrict__ best_idx,
                           int* __restrict__ best_has, int N, int Gn) {
    int g = blockIdx.x;
    int b = blockIdx.y;
    __shared__ float sv[256];
    __shared__ int si[256];
    float mx = -1.0f;
    int mi = 0x7FFFFFFF;
    for (int n = threadIdx.x; n < N; n += blockDim.x) {
        float v = iou[((size_t)b * N + n) * Gn + g];
        if (v > mx) { mx = v; mi = n; }
    }
    sv[threadIdx.x] = mx;
    si[threadIdx.x] = mi;
    __syncthreads();
    for (int s = 128; s > 0; s >>= 1) {
        if (threadIdx.x < s) {
            float v2 = sv[threadIdx.x + s];
            int i2 = si[threadIdx.x + s];
            if (v2 > sv[threadIdx.x] || (v2 == sv[threadIdx.x] && i2 < si[threadIdx.x])) {
                sv[threadIdx.x] = v2;
                si[threadIdx.x] = i2;
            }
        }
        __syncthreads();
    }
    if (threadIdx.x == 0) {
        best_idx[b * Gn + g] = si[0];
        best_has[b * Gn + g] = (sv[0] > 0.0f) ? 1 : 0;
    }
}

// Sequential low-quality force-match, one thread per image (matches the
// reference's sequential python loop over gts exactly).
__global__ void force_kernel(const int* __restrict__ best_idx, const int* __restrict__ best_has,
                             const int* __restrict__ gtl, int* __restrict__ lab,
                             int* __restrict__ mgidx, int N, int Gn, int Bn) {
    int b = threadIdx.x;
    if (b >= Bn) return;
    for (int j = 0; j < Gn; j++) {
        if (!best_has[b * Gn + j]) continue;
        int bi = best_idx[b * Gn + j];
        int lj = gtl[b * Gn + j] + 1;
        if (lab[b * N + bi] != lj) {
            lab[b * N + bi] = lj;
            mgidx[b * N + bi] = j;
        }
    }
}

__global__ void init_kernel(float* __restrict__ accum, int Bn) {
    int t = threadIdx.x;
    if (t < 3 * Bn) accum[t] = 0.0f;
}

// Per-anchor focal + smooth-L1, block reduce, atomicAdd per image.
__global__ void loss_kernel(const float* __restrict__ logits, const float* __restrict__ breg,
                            const float* __restrict__ anchors, const float* __restrict__ gtb,
                            const int* __restrict__ lab, const int* __restrict__ mgidx,
                            float* __restrict__ accum, int N, int Gn, int Cc) {
    int b = blockIdx.y;
    int n = blockIdx.x * blockDim.x + threadIdx.x;
    float cl = 0.0f, rl = 0.0f, npos = 0.0f;
    if (n < N) {
        int l = lab[b * N + n];
        if (l >= 0) {  // valid (pos or neg)
            const float* lg = logits + ((size_t)b * N + n) * Cc;
            int tc = l - 1;  // meaningful only when l > 0
            for (int c = 0; c < Cc; c++) {
                float x = lg[c];
                float fl;
                if (l > 0 && c == tc) {
                    // t = 1: alpha 0.25, (1-p)^2 * softplus(-x)
                    float omp = 1.0f / (1.0f + expf(x));  // 1 - sigmoid(x)
                    fl = 0.25f * omp * omp * softplusf(-x);
                } else {
                    // t = 0: alpha 0.75, p^2 * softplus(x)
                    float p = 1.0f / (1.0f + expf(-x));
                    fl = 0.75f * p * p * softplusf(x);
                }
                cl += fl;
            }
        }
        if (l > 0) {  // positive: regression term
            npos = 1.0f;
            const float* A = anchors + n * 5;
            const float* Gt = gtb + ((size_t)b * Gn + mgidx[b * N + n]) * 5;
            float ax = A[0], ay = A[1], aw = A[2], ah = A[3], at = A[4];
            float d0 = (Gt[0] - ax) / aw;
            float d1 = (Gt[1] - ay) / ah;
            float d2 = logf(Gt[2] / aw);
            float d3 = logf(Gt[3] / ah);
            float dth = remf180(Gt[4] - at + 90.0f) - 90.0f;
            const float* br = breg + ((size_t)b * N + n) * 5;
            float s4 = sl1(fabsf(br[0] - d0)) + sl1(fabsf(br[1] - d1)) +
                       sl1(fabsf(br[2] - d2)) + sl1(fabsf(br[3] - d3));
            float da = fabsf(remf180(br[4] - dth + 90.0f) - 90.0f);
            rl = s4 + sl1(da);
        }
    }
    __shared__ float s0[256], s1[256], s2[256];
    int tx = threadIdx.x;
    s0[tx] = cl; s1[tx] = rl; s2[tx] = npos;
    __syncthreads();
    for (int s = 128; s > 0; s >>= 1) {
        if (tx < s) {
            s0[tx] += s0[tx + s];
            s1[tx] += s1[tx + s];
            s2[tx] += s2[tx + s];
        }
        __syncthreads();
    }
    if (tx == 0) {
        atomicAdd(&accum[b * 3 + 0], s0[0]);
        atomicAdd(&accum[b * 3 + 1], s1[0]);
        atomicAdd(&accum[b * 3 + 2], s2[0]);
    }
}

__global__ void fin_kernel(const float* __restrict__ accum, float* __restrict__ out, int Bn) {
    if (threadIdx.x == 0 && blockIdx.x == 0) {
        float cm = 0.0f, rm = 0.0f;
        for (int b = 0; b < Bn; b++) {
            float np = fmaxf(accum[b * 3 + 2], 1.0f);
            cm += accum[b * 3 + 0] / np;
            rm += accum[b * 3 + 1] / np;  // REG_WEIGHT = 1
        }
        cm /= (float)Bn;
        rm /= (float)Bn;
        out[0] = cm + rm;
        out[1] = cm;
        out[2] = rm;
    }
}

extern "C" void kernel_launch(void* const* d_in, const int* in_sizes, int n_in,
                              void* d_out, int out_size, void* d_ws, size_t ws_size,
                              hipStream_t stream) {
    const float* logits  = (const float*)d_in[0];
    const float* breg    = (const float*)d_in[1];
    const float* anchors = (const float*)d_in[2];
    const float* gtb     = (const float*)d_in[3];
    const int*   gtl     = (const int*)d_in[4];

    int N  = in_sizes[2] / 5;           // anchors: (N,5)
    int Bn = in_sizes[1] / (N * 5);     // box_regression: (B,N,5)
    int Gn = in_sizes[4] / Bn;          // gt_labels: (B,G)
    int Cc = in_sizes[0] / (Bn * N);    // cls_logits: (B,N,C)

    float* out = (float*)d_out;

    char* w = (char*)d_ws;
    float* iou = (float*)w;      w += sizeof(float) * (size_t)Bn * N * Gn;
    int* lab = (int*)w;          w += sizeof(int) * (size_t)Bn * N;
    int* mgidx = (int*)w;        w += sizeof(int) * (size_t)Bn * N;
    int* best_idx = (int*)w;     w += sizeof(int) * Bn * Gn;
    int* best_has = (int*)w;     w += sizeof(int) * Bn * Gn;
    float* accum = (float*)w;    w += sizeof(float) * 3 * Bn;

    int total = Bn * N * Gn;
    iou_kernel<<<dim3((total + 255) / 256), dim3(256), 0, stream>>>(anchors, gtb, iou, N, Gn, Bn);
    row_kernel<<<dim3((Bn * N + 255) / 256), dim3(256), 0, stream>>>(iou, gtl, lab, mgidx, N, Gn, Bn);
    col_kernel<<<dim3(Gn, Bn), dim3(256), 0, stream>>>(iou, best_idx, best_has, N, Gn);
    force_kernel<<<dim3(1), dim3(64), 0, stream>>>(best_idx, best_has, gtl, lab, mgidx, N, Gn, Bn);
    init_kernel<<<dim3(1), dim3(64), 0, stream>>>(accum, Bn);
    loss_kernel<<<dim3((N + 255) / 256, Bn), dim3(256), 0, stream>>>(logits, breg, anchors, gtb,
                                                                     lab, mgidx, accum, N, Gn, Cc);
    fin_kernel<<<dim3(1), dim3(1), 0, stream>>>(accum, out, Bn);
}

// Round 2
// 223.206 us; speedup vs baseline: 1.5697x; 1.5697x over previous
//
#include <hip/hip_runtime.h>
#include <math.h>

#define DEG2RAD_F 0.017453292519943295f

__device__ __forceinline__ float sl1(float d) {
    return (d < 1.0f) ? (0.5f * d * d) : (d - 0.5f);
}

__device__ __forceinline__ float remf180(float x) {
    float r = fmodf(x, 180.0f);
    if (r < 0.0f) r += 180.0f;
    return r;
}

__device__ __forceinline__ float softplusf(float x) {
    if (x > 0.0f) return x + log1pf(expf(-x));
    return log1pf(expf(x));
}

__device__ __forceinline__ void box_corners(float cx, float cy, float w, float h, float t,
                                            float* X, float* Y) {
    float r = t * DEG2RAD_F;
    float c = cosf(r), s = sinf(r);
    const float sx[4] = {-0.5f, 0.5f, 0.5f, -0.5f};
    const float sy[4] = {-0.5f, -0.5f, 0.5f, 0.5f};
#pragma unroll
    for (int i = 0; i < 4; i++) {
        float lx = w * sx[i], ly = h * sy[i];
        X[i] = cx + lx * c - ly * s;
        Y[i] = cy + lx * s + ly * c;
    }
}

// Exact quad-quad intersection area, register-resident: all arrays are
// indexed with compile-time constants only (SROA -> VGPRs, no scratch).
// Sort = stable odd-even transposition network (strict > swap) on a
// monotone pseudo-angle key (same ordering as atan2).
__device__ __forceinline__ float quad_inter_area(const float* p1x, const float* p1y,
                                                 const float* p2x, const float* p2y) {
    float X[24], Y[24];
    bool M[24];

    // p1 corners inside p2?
#pragma unroll
    for (int i = 0; i < 4; i++) {
        X[i] = p1x[i];
        Y[i] = p1y[i];
        bool ins = true;
#pragma unroll
        for (int k = 0; k < 4; k++) {
            int k2 = (k + 1) & 3;
            float ex = p2x[k2] - p2x[k], ey = p2y[k2] - p2y[k];
            float dx = p1x[i] - p2x[k], dy = p1y[i] - p2y[k];
            ins = ins && (ex * dy - ey * dx >= -1e-6f);
        }
        M[i] = ins;
    }
    // p2 corners inside p1?
#pragma unroll
    for (int i = 0; i < 4; i++) {
        X[4 + i] = p2x[i];
        Y[4 + i] = p2y[i];
        bool ins = true;
#pragma unroll
        for (int k = 0; k < 4; k++) {
            int k2 = (k + 1) & 3;
            float ex = p1x[k2] - p1x[k], ey = p1y[k2] - p1y[k];
            float dx = p2x[i] - p1x[k], dy = p2y[i] - p1y[k];
            ins = ins && (ex * dy - ey * dx >= -1e-6f);
        }
        M[4 + i] = ins;
    }
    // 16 edge-edge intersections
#pragma unroll
    for (int i = 0; i < 4; i++) {
        int i2 = (i + 1) & 3;
        float ax = p1x[i], ay = p1y[i];
        float rx = p1x[i2] - ax, ry = p1y[i2] - ay;
#pragma unroll
        for (int j = 0; j < 4; j++) {
            int j2 = (j + 1) & 3;
            float cx = p2x[j], cy = p2y[j];
            float ux = p2x[j2] - cx, uy = p2y[j2] - cy;
            float qx = cx - ax, qy = cy - ay;
            float den = rx * uy - ry * ux;
            bool dok = fabsf(den) > 1e-10f;
            float safe = dok ? den : 1.0f;
            float t = (qx * uy - qy * ux) / safe;
            float s = (qx * ry - qy * rx) / safe;
            int idx = 8 + i * 4 + j;
            X[idx] = ax + t * rx;
            Y[idx] = ay + t * ry;
            M[idx] = dok && (t >= 0.0f) && (t <= 1.0f) && (s >= 0.0f) && (s <= 1.0f);
        }
    }

    // count + centroid (branchless)
    int n = 0;
    float sx = 0.0f, sy = 0.0f;
#pragma unroll
    for (int i = 0; i < 24; i++) {
        n += M[i] ? 1 : 0;
        sx += M[i] ? X[i] : 0.0f;
        sy += M[i] ? Y[i] : 0.0f;
    }
    float denom = (float)(n > 1 ? n : 1);
    float cenx = sx / denom, ceny = sy / denom;

    // first valid point via predicated scan (no dynamic index)
    bool found = false;
    float rfx = X[0], rfy = Y[0];
#pragma unroll
    for (int i = 0; i < 24; i++) {
        bool take = M[i] && !found;
        rfx = take ? X[i] : rfx;
        rfy = take ? Y[i] : rfy;
        found = found || M[i];
    }

    // replace invalid with ref point; pseudo-angle key (monotone in atan2)
    float K[24];
#pragma unroll
    for (int i = 0; i < 24; i++) {
        float xx = M[i] ? X[i] : rfx;
        float yy = M[i] ? Y[i] : rfy;
        X[i] = xx;
        Y[i] = yy;
        float dx = xx - cenx, dy = yy - ceny;
        float ad = fabsf(dx) + fabsf(dy);
        float pg = dy / ad;
        float k = (dx >= 0.0f) ? pg : ((dy >= 0.0f) ? 2.0f - pg : -2.0f - pg);
        K[i] = (ad > 0.0f) ? k : 0.0f;  // guard point==centroid (atan2(0,0)=0)
    }

    // stable odd-even transposition sort, ascending (strict > swap == stable)
#pragma unroll
    for (int r = 0; r < 24; r++) {
#pragma unroll
        for (int i = (r & 1); i < 23; i += 2) {
            bool sw = K[i] > K[i + 1];
            float tk = K[i], tx = X[i], ty = Y[i];
            K[i] = sw ? K[i + 1] : K[i];
            X[i] = sw ? X[i + 1] : X[i];
            Y[i] = sw ? Y[i + 1] : Y[i];
            K[i + 1] = sw ? tk : K[i + 1];
            X[i + 1] = sw ? tx : X[i + 1];
            Y[i + 1] = sw ? ty : Y[i + 1];
        }
    }

    // shoelace over sorted ring
    float a2 = 0.0f;
#pragma unroll
    for (int i = 0; i < 24; i++) {
        int j = (i + 1) % 24;
        a2 += X[i] * Y[j] - X[j] * Y[i];
    }
    return (n >= 3) ? 0.5f * fabsf(a2) : 0.0f;
}

// Gate pass: zero-fill iou matrix and compact passing (b,n,g) pairs.
__global__ void gate_kernel(const float* __restrict__ anchors, const float* __restrict__ gtb,
                            float* __restrict__ iou, int* __restrict__ counter,
                            int* __restrict__ list, int N, int Gn, int Bn) {
    int tid = blockIdx.x * blockDim.x + threadIdx.x;
    int total = Bn * N * Gn;
    if (tid >= total) return;
    int g = tid % Gn;
    int rem = tid / Gn;
    int n = rem % N;
    int b = rem / N;

    const float* A = anchors + n * 5;
    const float* Gt = gtb + (b * Gn + g) * 5;
    float asz = fmaxf(A[2], A[3]), gsz = fmaxf(Gt[2], Gt[3]);
    float dx = A[0] - Gt[0], dy = A[1] - Gt[1];
    float dist = sqrtf(dx * dx + dy * dy);

    iou[tid] = 0.0f;
    if (dist < 0.7f * (asz + gsz)) {
        int idx = atomicAdd(counter, 1);
        list[idx] = tid;
    }
}

// Heavy pass: dense waves over compacted candidates, exact rotated IoU.
__global__ void heavy_kernel(const float* __restrict__ anchors, const float* __restrict__ gtb,
                             const int* __restrict__ counter, const int* __restrict__ list,
                             float* __restrict__ iou, int N, int Gn) {
    int i = blockIdx.x * blockDim.x + threadIdx.x;
    if (i >= *counter) return;
    int tid = list[i];
    int g = tid % Gn;
    int rem = tid / Gn;
    int n = rem % N;
    int b = rem / N;

    const float* A = anchors + n * 5;
    const float* Gt = gtb + (b * Gn + g) * 5;
    float aw = A[2], ah = A[3];
    float gw = Gt[2], gh = Gt[3];

    float p1x[4], p1y[4], p2x[4], p2y[4];
    box_corners(A[0], A[1], aw, ah, A[4], p1x, p1y);
    box_corners(Gt[0], Gt[1], gw, gh, Gt[4], p2x, p2y);
    float inter = quad_inter_area(p1x, p1y, p2x, p2y);
    iou[tid] = inter / (aw * ah + gw * gh - inter + 1e-8f);
}

// Fused row-argmax (per anchor) + col-argmax (per gt).
__global__ void rowcol_kernel(const float* __restrict__ iou, const int* __restrict__ gtl,
                              int* __restrict__ lab, int* __restrict__ mgidx,
                              int* __restrict__ best_idx, int* __restrict__ best_has,
                              int N, int Gn, int Bn) {
    __shared__ float sv[256];
    __shared__ int si[256];
    int nRow = (Bn * N + 255) / 256;
    if ((int)blockIdx.x < nRow) {
        int tid = blockIdx.x * 256 + threadIdx.x;
        if (tid >= Bn * N) return;
        int b = tid / N;
        const float* row = iou + (size_t)tid * Gn;
        float mx = row[0];
        int mi = 0;
        for (int g = 1; g < Gn; g++) {
            float v = row[g];
            if (v > mx) { mx = v; mi = g; }
        }
        int l, mg = -1;
        if (mx >= 0.5f) {
            l = gtl[b * Gn + mi] + 1;
            mg = mi;
        } else if (mx < 0.4f) {
            l = 0;
        } else {
            l = -1;
        }
        lab[tid] = l;
        mgidx[tid] = mg;
    } else {
        int id = blockIdx.x - nRow;  // 0 .. Bn*Gn-1
        int g = id % Gn;
        int b = id / Gn;
        float mx = -1.0f;
        int mi = 0x7FFFFFFF;
        for (int n = threadIdx.x; n < N; n += 256) {
            float v = iou[((size_t)b * N + n) * Gn + g];
            if (v > mx) { mx = v; mi = n; }
        }
        sv[threadIdx.x] = mx;
        si[threadIdx.x] = mi;
        __syncthreads();
        for (int s = 128; s > 0; s >>= 1) {
            if ((int)threadIdx.x < s) {
                float v2 = sv[threadIdx.x + s];
                int i2 = si[threadIdx.x + s];
                if (v2 > sv[threadIdx.x] ||
                    (v2 == sv[threadIdx.x] && i2 < si[threadIdx.x])) {
                    sv[threadIdx.x] = v2;
                    si[threadIdx.x] = i2;
                }
            }
            __syncthreads();
        }
        if (threadIdx.x == 0) {
            best_idx[b * Gn + g] = si[0];
            best_has[b * Gn + g] = (sv[0] > 0.0f) ? 1 : 0;
        }
    }
}

// Sequential low-quality force-match (matches reference python loop exactly).
__global__ void force_kernel(const int* __restrict__ best_idx, const int* __restrict__ best_has,
                             const int* __restrict__ gtl, int* __restrict__ lab,
                             int* __restrict__ mgidx, int N, int Gn, int Bn) {
    int b = threadIdx.x;
    if (b >= Bn) return;
    for (int j = 0; j < Gn; j++) {
        if (!best_has[b * Gn + j]) continue;
        int bi = best_idx[b * Gn + j];
        int lj = gtl[b * Gn + j] + 1;
        if (lab[b * N + bi] != lj) {
            lab[b * N + bi] = lj;
            mgidx[b * N + bi] = j;
        }
    }
}

// Per-anchor focal + smooth-L1, block reduce, atomicAdd per image.
__global__ void loss_kernel(const float* __restrict__ logits, const float* __restrict__ breg,
                            const float* __restrict__ anchors, const float* __restrict__ gtb,
                            const int* __restrict__ lab, const int* __restrict__ mgidx,
                            float* __restrict__ accum, int N, int Gn, int Cc) {
    int b = blockIdx.y;
    int n = blockIdx.x * blockDim.x + threadIdx.x;
    float cl = 0.0f, rl = 0.0f, npos = 0.0f;
    if (n < N) {
        int l = lab[b * N + n];
        if (l >= 0) {
            const float* lg = logits + ((size_t)b * N + n) * Cc;
            int tc = l - 1;
            for (int c = 0; c < Cc; c++) {
                float x = lg[c];
                float fl;
                if (l > 0 && c == tc) {
                    float omp = 1.0f / (1.0f + expf(x));
                    fl = 0.25f * omp * omp * softplusf(-x);
                } else {
                    float p = 1.0f / (1.0f + expf(-x));
                    fl = 0.75f * p * p * softplusf(x);
                }
                cl += fl;
            }
        }
        if (l > 0) {
            npos = 1.0f;
            const float* A = anchors + n * 5;
            const float* Gt = gtb + ((size_t)b * Gn + mgidx[b * N + n]) * 5;
            float ax = A[0], ay = A[1], aw = A[2], ah = A[3], at = A[4];
            float d0 = (Gt[0] - ax) / aw;
            float d1 = (Gt[1] - ay) / ah;
            float d2 = logf(Gt[2] / aw);
            float d3 = logf(Gt[3] / ah);
            float dth = remf180(Gt[4] - at + 90.0f) - 90.0f;
            const float* br = breg + ((size_t)b * N + n) * 5;
            float s4 = sl1(fabsf(br[0] - d0)) + sl1(fabsf(br[1] - d1)) +
                       sl1(fabsf(br[2] - d2)) + sl1(fabsf(br[3] - d3));
            float da = fabsf(remf180(br[4] - dth + 90.0f) - 90.0f);
            rl = s4 + sl1(da);
        }
    }
    __shared__ float s0[256], s1[256], s2[256];
    int tx = threadIdx.x;
    s0[tx] = cl; s1[tx] = rl; s2[tx] = npos;
    __syncthreads();
    for (int s = 128; s > 0; s >>= 1) {
        if (tx < s) {
            s0[tx] += s0[tx + s];
            s1[tx] += s1[tx + s];
            s2[tx] += s2[tx + s];
        }
        __syncthreads();
    }
    if (tx == 0) {
        atomicAdd(&accum[b * 3 + 0], s0[0]);
        atomicAdd(&accum[b * 3 + 1], s1[0]);
        atomicAdd(&accum[b * 3 + 2], s2[0]);
    }
}

__global__ void fin_kernel(const float* __restrict__ accum, float* __restrict__ out, int Bn) {
    if (threadIdx.x == 0 && blockIdx.x == 0) {
        float cm = 0.0f, rm = 0.0f;
        for (int b = 0; b < Bn; b++) {
            float np = fmaxf(accum[b * 3 + 2], 1.0f);
            cm += accum[b * 3 + 0] / np;
            rm += accum[b * 3 + 1] / np;
        }
        cm /= (float)Bn;
        rm /= (float)Bn;
        out[0] = cm + rm;
        out[1] = cm;
        out[2] = rm;
    }
}

extern "C" void kernel_launch(void* const* d_in, const int* in_sizes, int n_in,
                              void* d_out, int out_size, void* d_ws, size_t ws_size,
                              hipStream_t stream) {
    const float* logits  = (const float*)d_in[0];
    const float* breg    = (const float*)d_in[1];
    const float* anchors = (const float*)d_in[2];
    const float* gtb     = (const float*)d_in[3];
    const int*   gtl     = (const int*)d_in[4];

    int N  = in_sizes[2] / 5;           // anchors: (N,5)
    int Bn = in_sizes[1] / (N * 5);     // box_regression: (B,N,5)
    int Gn = in_sizes[4] / Bn;          // gt_labels: (B,G)
    int Cc = in_sizes[0] / (Bn * N);    // cls_logits: (B,N,C)

    float* out = (float*)d_out;

    char* w = (char*)d_ws;
    float* iou = (float*)w;      w += sizeof(float) * (size_t)Bn * N * Gn;
    int* list = (int*)w;         w += sizeof(int) * (size_t)Bn * N * Gn;
    int* lab = (int*)w;          w += sizeof(int) * (size_t)Bn * N;
    int* mgidx = (int*)w;        w += sizeof(int) * (size_t)Bn * N;
    int* best_idx = (int*)w;     w += sizeof(int) * Bn * Gn;
    int* best_has = (int*)w;     w += sizeof(int) * Bn * Gn;
    int* counter = (int*)w;      w += sizeof(int);
    float* accum = (float*)w;    w += sizeof(float) * 3 * Bn;

    // zero counter + accum in one async memset (graph-capturable)
    hipMemsetAsync(counter, 0, sizeof(int) + sizeof(float) * 3 * Bn, stream);

    int total = Bn * N * Gn;
    int nPairBlocks = (total + 255) / 256;
    gate_kernel<<<dim3(nPairBlocks), dim3(256), 0, stream>>>(anchors, gtb, iou, counter, list,
                                                             N, Gn, Bn);
    heavy_kernel<<<dim3(nPairBlocks), dim3(256), 0, stream>>>(anchors, gtb, counter, list, iou,
                                                              N, Gn);
    int nRow = (Bn * N + 255) / 256;
    rowcol_kernel<<<dim3(nRow + Bn * Gn), dim3(256), 0, stream>>>(iou, gtl, lab, mgidx,
                                                                  best_idx, best_has, N, Gn, Bn);
    force_kernel<<<dim3(1), dim3(64), 0, stream>>>(best_idx, best_has, gtl, lab, mgidx, N, Gn, Bn);
    loss_kernel<<<dim3((N + 255) / 256, Bn), dim3(256), 0, stream>>>(logits, breg, anchors, gtb,
                                                                     lab, mgidx, accum, N, Gn, Cc);
    fin_kernel<<<dim3(1), dim3(1), 0, stream>>>(accum, out, Bn);
}

// Round 3
// 138.683 us; speedup vs baseline: 2.5264x; 1.6095x over previous
//
#include <hip/hip_runtime.h>
#include <math.h>

#define DEG2RAD_F 0.017453292519943295f
#define GATE_ITERS 8

__device__ __forceinline__ float sl1(float d) {
    return (d < 1.0f) ? (0.5f * d * d) : (d - 0.5f);
}

__device__ __forceinline__ float remf180(float x) {
    float r = fmodf(x, 180.0f);
    if (r < 0.0f) r += 180.0f;
    return r;
}

__device__ __forceinline__ float softplusf(float x) {
    if (x > 0.0f) return x + log1pf(expf(-x));
    return log1pf(expf(x));
}

__device__ __forceinline__ void box_corners(float cx, float cy, float w, float h, float t,
                                            float* X, float* Y) {
    float r = t * DEG2RAD_F;
    float c = cosf(r), s = sinf(r);
    const float sx[4] = {-0.5f, 0.5f, 0.5f, -0.5f};
    const float sy[4] = {-0.5f, -0.5f, 0.5f, 0.5f};
#pragma unroll
    for (int i = 0; i < 4; i++) {
        float lx = w * sx[i], ly = h * sy[i];
        X[i] = cx + lx * c - ly * s;
        Y[i] = cy + lx * s + ly * c;
    }
}

// Exact quad-quad intersection area, register-resident (constant indices only).
__device__ __forceinline__ float quad_inter_area(const float* p1x, const float* p1y,
                                                 const float* p2x, const float* p2y) {
    float X[24], Y[24];
    bool M[24];

#pragma unroll
    for (int i = 0; i < 4; i++) {
        X[i] = p1x[i];
        Y[i] = p1y[i];
        bool ins = true;
#pragma unroll
        for (int k = 0; k < 4; k++) {
            int k2 = (k + 1) & 3;
            float ex = p2x[k2] - p2x[k], ey = p2y[k2] - p2y[k];
            float dx = p1x[i] - p2x[k], dy = p1y[i] - p2y[k];
            ins = ins && (ex * dy - ey * dx >= -1e-6f);
        }
        M[i] = ins;
    }
#pragma unroll
    for (int i = 0; i < 4; i++) {
        X[4 + i] = p2x[i];
        Y[4 + i] = p2y[i];
        bool ins = true;
#pragma unroll
        for (int k = 0; k < 4; k++) {
            int k2 = (k + 1) & 3;
            float ex = p1x[k2] - p1x[k], ey = p1y[k2] - p1y[k];
            float dx = p2x[i] - p1x[k], dy = p2y[i] - p1y[k];
            ins = ins && (ex * dy - ey * dx >= -1e-6f);
        }
        M[4 + i] = ins;
    }
#pragma unroll
    for (int i = 0; i < 4; i++) {
        int i2 = (i + 1) & 3;
        float ax = p1x[i], ay = p1y[i];
        float rx = p1x[i2] - ax, ry = p1y[i2] - ay;
#pragma unroll
        for (int j = 0; j < 4; j++) {
            int j2 = (j + 1) & 3;
            float cx = p2x[j], cy = p2y[j];
            float ux = p2x[j2] - cx, uy = p2y[j2] - cy;
            float qx = cx - ax, qy = cy - ay;
            float den = rx * uy - ry * ux;
            bool dok = fabsf(den) > 1e-10f;
            float safe = dok ? den : 1.0f;
            float t = (qx * uy - qy * ux) / safe;
            float s = (qx * ry - qy * rx) / safe;
            int idx = 8 + i * 4 + j;
            X[idx] = ax + t * rx;
            Y[idx] = ay + t * ry;
            M[idx] = dok && (t >= 0.0f) && (t <= 1.0f) && (s >= 0.0f) && (s <= 1.0f);
        }
    }

    int n = 0;
    float sx = 0.0f, sy = 0.0f;
#pragma unroll
    for (int i = 0; i < 24; i++) {
        n += M[i] ? 1 : 0;
        sx += M[i] ? X[i] : 0.0f;
        sy += M[i] ? Y[i] : 0.0f;
    }
    float denom = (float)(n > 1 ? n : 1);
    float cenx = sx / denom, ceny = sy / denom;

    bool found = false;
    float rfx = X[0], rfy = Y[0];
#pragma unroll
    for (int i = 0; i < 24; i++) {
        bool take = M[i] && !found;
        rfx = take ? X[i] : rfx;
        rfy = take ? Y[i] : rfy;
        found = found || M[i];
    }

    float K[24];
#pragma unroll
    for (int i = 0; i < 24; i++) {
        float xx = M[i] ? X[i] : rfx;
        float yy = M[i] ? Y[i] : rfy;
        X[i] = xx;
        Y[i] = yy;
        float dx = xx - cenx, dy = yy - ceny;
        float ad = fabsf(dx) + fabsf(dy);
        float pg = dy / ad;
        float k = (dx >= 0.0f) ? pg : ((dy >= 0.0f) ? 2.0f - pg : -2.0f - pg);
        K[i] = (ad > 0.0f) ? k : 0.0f;
    }

    // stable odd-even transposition sort, ascending (strict > swap == stable)
#pragma unroll
    for (int r = 0; r < 24; r++) {
#pragma unroll
        for (int i = (r & 1); i < 23; i += 2) {
            bool sw = K[i] > K[i + 1];
            float tk = K[i], tx = X[i], ty = Y[i];
            K[i] = sw ? K[i + 1] : K[i];
            X[i] = sw ? X[i + 1] : X[i];
            Y[i] = sw ? Y[i + 1] : Y[i];
            K[i + 1] = sw ? tk : K[i + 1];
            X[i + 1] = sw ? tx : X[i + 1];
            Y[i + 1] = sw ? ty : Y[i + 1];
        }
    }

    float a2 = 0.0f;
#pragma unroll
    for (int i = 0; i < 24; i++) {
        int j = (i + 1) % 24;
        a2 += X[i] * Y[j] - X[j] * Y[i];
    }
    return (n >= 3) ? 0.5f * fabsf(a2) : 0.0f;
}

// Gate pass with block-level compaction: 8 pairs/thread grid-stride,
// LDS prefix scan of per-thread pass counts, ONE atomicAdd per block.
__global__ void gate_kernel(const float* __restrict__ anchors, const float* __restrict__ gtb,
                            float* __restrict__ iou, int* __restrict__ counter,
                            int* __restrict__ list, int N, int Gn, int Bn, int total) {
    int tx = threadIdx.x;
    int base = blockIdx.x * blockDim.x + tx;
    int stride = gridDim.x * blockDim.x;

    bool pf[GATE_ITERS];
    int pt[GATE_ITERS];
    int cnt = 0;
#pragma unroll
    for (int it = 0; it < GATE_ITERS; it++) {
        int tid = base + it * stride;
        bool pass = false;
        if (tid < total) {
            int g = tid % Gn;
            int rem = tid / Gn;
            int n = rem % N;
            int b = rem / N;
            const float* A = anchors + n * 5;
            const float* Gt = gtb + (b * Gn + g) * 5;
            float asz = fmaxf(A[2], A[3]), gsz = fmaxf(Gt[2], Gt[3]);
            float dx = A[0] - Gt[0], dy = A[1] - Gt[1];
            iou[tid] = 0.0f;
            pass = sqrtf(dx * dx + dy * dy) < 0.7f * (asz + gsz);
        }
        pf[it] = pass;
        pt[it] = tid;
        cnt += pass ? 1 : 0;
    }

    __shared__ int sc[256];
    __shared__ int sbase;
    sc[tx] = cnt;
    __syncthreads();
    // Hillis-Steele inclusive scan over 256 threads
    for (int d = 1; d < 256; d <<= 1) {
        int v = (tx >= d) ? sc[tx - d] : 0;
        __syncthreads();
        sc[tx] += v;
        __syncthreads();
    }
    if (tx == 255) sbase = atomicAdd(counter, sc[255]);
    __syncthreads();

    int off = sbase + sc[tx] - cnt;  // exclusive prefix + block base
#pragma unroll
    for (int it = 0; it < GATE_ITERS; it++) {
        if (pf[it]) list[off++] = pt[it];
    }
}

// Heavy pass: dense waves over compacted candidates, exact rotated IoU.
__global__ void heavy_kernel(const float* __restrict__ anchors, const float* __restrict__ gtb,
                             const int* __restrict__ counter, const int* __restrict__ list,
                             float* __restrict__ iou, int N, int Gn) {
    int i = blockIdx.x * blockDim.x + threadIdx.x;
    if (i >= *counter) return;
    int tid = list[i];
    int g = tid % Gn;
    int rem = tid / Gn;
    int n = rem % N;
    int b = rem / N;

    const float* A = anchors + n * 5;
    const float* Gt = gtb + (b * Gn + g) * 5;
    float aw = A[2], ah = A[3];
    float gw = Gt[2], gh = Gt[3];

    float p1x[4], p1y[4], p2x[4], p2y[4];
    box_corners(A[0], A[1], aw, ah, A[4], p1x, p1y);
    box_corners(Gt[0], Gt[1], gw, gh, Gt[4], p2x, p2y);
    float inter = quad_inter_area(p1x, p1y, p2x, p2y);
    iou[tid] = inter / (aw * ah + gw * gh - inter + 1e-8f);
}

// Fused row-argmax (per anchor) + col-argmax (per gt).
__global__ void rowcol_kernel(const float* __restrict__ iou, const int* __restrict__ gtl,
                              int* __restrict__ lab, int* __restrict__ mgidx,
                              int* __restrict__ best_idx, int* __restrict__ best_has,
                              int N, int Gn, int Bn) {
    __shared__ float sv[256];
    __shared__ int si[256];
    int nRow = (Bn * N + 255) / 256;
    if ((int)blockIdx.x < nRow) {
        int tid = blockIdx.x * 256 + threadIdx.x;
        if (tid >= Bn * N) return;
        int b = tid / N;
        const float* row = iou + (size_t)tid * Gn;
        float mx = row[0];
        int mi = 0;
        for (int g = 1; g < Gn; g++) {
            float v = row[g];
            if (v > mx) { mx = v; mi = g; }
        }
        int l, mg = -1;
        if (mx >= 0.5f) {
            l = gtl[b * Gn + mi] + 1;
            mg = mi;
        } else if (mx < 0.4f) {
            l = 0;
        } else {
            l = -1;
        }
        lab[tid] = l;
        mgidx[tid] = mg;
    } else {
        int id = blockIdx.x - nRow;  // 0 .. Bn*Gn-1
        int g = id % Gn;
        int b = id / Gn;
        float mx = -1.0f;
        int mi = 0x7FFFFFFF;
        for (int n = threadIdx.x; n < N; n += 256) {
            float v = iou[((size_t)b * N + n) * Gn + g];
            if (v > mx) { mx = v; mi = n; }
        }
        sv[threadIdx.x] = mx;
        si[threadIdx.x] = mi;
        __syncthreads();
        for (int s = 128; s > 0; s >>= 1) {
            if ((int)threadIdx.x < s) {
                float v2 = sv[threadIdx.x + s];
                int i2 = si[threadIdx.x + s];
                if (v2 > sv[threadIdx.x] ||
                    (v2 == sv[threadIdx.x] && i2 < si[threadIdx.x])) {
                    sv[threadIdx.x] = v2;
                    si[threadIdx.x] = i2;
                }
            }
            __syncthreads();
        }
        if (threadIdx.x == 0) {
            best_idx[b * Gn + g] = si[0];
            best_has[b * Gn + g] = (sv[0] > 0.0f) ? 1 : 0;
        }
    }
}

// Sequential low-quality force-match (matches reference python loop exactly).
__global__ void force_kernel(const int* __restrict__ best_idx, const int* __restrict__ best_has,
                             const int* __restrict__ gtl, int* __restrict__ lab,
                             int* __restrict__ mgidx, int N, int Gn, int Bn) {
    int b = threadIdx.x;
    if (b >= Bn) return;
    for (int j = 0; j < Gn; j++) {
        if (!best_has[b * Gn + j]) continue;
        int bi = best_idx[b * Gn + j];
        int lj = gtl[b * Gn + j] + 1;
        if (lab[b * N + bi] != lj) {
            lab[b * N + bi] = lj;
            mgidx[b * N + bi] = j;
        }
    }
}

// Per-anchor focal + smooth-L1, block reduce, atomicAdd per image.
__global__ void loss_kernel(const float* __restrict__ logits, const float* __restrict__ breg,
                            const float* __restrict__ anchors, const float* __restrict__ gtb,
                            const int* __restrict__ lab, const int* __restrict__ mgidx,
                            float* __restrict__ accum, int N, int Gn, int Cc) {
    int b = blockIdx.y;
    int n = blockIdx.x * blockDim.x + threadIdx.x;
    float cl = 0.0f, rl = 0.0f, npos = 0.0f;
    if (n < N) {
        int l = lab[b * N + n];
        if (l >= 0) {
            const float* lg = logits + ((size_t)b * N + n) * Cc;
            int tc = l - 1;
            for (int c = 0; c < Cc; c++) {
                float x = lg[c];
                float fl;
                if (l > 0 && c == tc) {
                    float omp = 1.0f / (1.0f + expf(x));
                    fl = 0.25f * omp * omp * softplusf(-x);
                } else {
                    float p = 1.0f / (1.0f + expf(-x));
                    fl = 0.75f * p * p * softplusf(x);
                }
                cl += fl;
            }
        }
        if (l > 0) {
            npos = 1.0f;
            const float* A = anchors + n * 5;
            const float* Gt = gtb + ((size_t)b * Gn + mgidx[b * N + n]) * 5;
            float ax = A[0], ay = A[1], aw = A[2], ah = A[3], at = A[4];
            float d0 = (Gt[0] - ax) / aw;
            float d1 = (Gt[1] - ay) / ah;
            float d2 = logf(Gt[2] / aw);
            float d3 = logf(Gt[3] / ah);
            float dth = remf180(Gt[4] - at + 90.0f) - 90.0f;
            const float* br = breg + ((size_t)b * N + n) * 5;
            float s4 = sl1(fabsf(br[0] - d0)) + sl1(fabsf(br[1] - d1)) +
                       sl1(fabsf(br[2] - d2)) + sl1(fabsf(br[3] - d3));
            float da = fabsf(remf180(br[4] - dth + 90.0f) - 90.0f);
            rl = s4 + sl1(da);
        }
    }
    __shared__ float s0[256], s1[256], s2[256];
    int tx = threadIdx.x;
    s0[tx] = cl; s1[tx] = rl; s2[tx] = npos;
    __syncthreads();
    for (int s = 128; s > 0; s >>= 1) {
        if (tx < s) {
            s0[tx] += s0[tx + s];
            s1[tx] += s1[tx + s];
            s2[tx] += s2[tx + s];
        }
        __syncthreads();
    }
    if (tx == 0) {
        atomicAdd(&accum[b * 3 + 0], s0[0]);
        atomicAdd(&accum[b * 3 + 1], s1[0]);
        atomicAdd(&accum[b * 3 + 2], s2[0]);
    }
}

__global__ void fin_kernel(const float* __restrict__ accum, float* __restrict__ out, int Bn) {
    if (threadIdx.x == 0 && blockIdx.x == 0) {
        float cm = 0.0f, rm = 0.0f;
        for (int b = 0; b < Bn; b++) {
            float np = fmaxf(accum[b * 3 + 2], 1.0f);
            cm += accum[b * 3 + 0] / np;
            rm += accum[b * 3 + 1] / np;
        }
        cm /= (float)Bn;
        rm /= (float)Bn;
        out[0] = cm + rm;
        out[1] = cm;
        out[2] = rm;
    }
}

extern "C" void kernel_launch(void* const* d_in, const int* in_sizes, int n_in,
                              void* d_out, int out_size, void* d_ws, size_t ws_size,
                              hipStream_t stream) {
    const float* logits  = (const float*)d_in[0];
    const float* breg    = (const float*)d_in[1];
    const float* anchors = (const float*)d_in[2];
    const float* gtb     = (const float*)d_in[3];
    const int*   gtl     = (const int*)d_in[4];

    int N  = in_sizes[2] / 5;           // anchors: (N,5)
    int Bn = in_sizes[1] / (N * 5);     // box_regression: (B,N,5)
    int Gn = in_sizes[4] / Bn;          // gt_labels: (B,G)
    int Cc = in_sizes[0] / (Bn * N);    // cls_logits: (B,N,C)

    float* out = (float*)d_out;

    char* w = (char*)d_ws;
    float* iou = (float*)w;      w += sizeof(float) * (size_t)Bn * N * Gn;
    int* list = (int*)w;         w += sizeof(int) * (size_t)Bn * N * Gn;
    int* lab = (int*)w;          w += sizeof(int) * (size_t)Bn * N;
    int* mgidx = (int*)w;        w += sizeof(int) * (size_t)Bn * N;
    int* best_idx = (int*)w;     w += sizeof(int) * Bn * Gn;
    int* best_has = (int*)w;     w += sizeof(int) * Bn * Gn;
    int* counter = (int*)w;      w += sizeof(int);
    float* accum = (float*)w;    w += sizeof(float) * 3 * Bn;

    hipMemsetAsync(counter, 0, sizeof(int) + sizeof(float) * 3 * Bn, stream);

    int total = Bn * N * Gn;
    int nGateBlocks = (total + 256 * GATE_ITERS - 1) / (256 * GATE_ITERS);
    gate_kernel<<<dim3(nGateBlocks), dim3(256), 0, stream>>>(anchors, gtb, iou, counter, list,
                                                             N, Gn, Bn, total);
    int nPairBlocks = (total + 255) / 256;
    heavy_kernel<<<dim3(nPairBlocks), dim3(256), 0, stream>>>(anchors, gtb, counter, list, iou,
                                                              N, Gn);
    int nRow = (Bn * N + 255) / 256;
    rowcol_kernel<<<dim3(nRow + Bn * Gn), dim3(256), 0, stream>>>(iou, gtl, lab, mgidx,
                                                                  best_idx, best_has, N, Gn, Bn);
    force_kernel<<<dim3(1), dim3(64), 0, stream>>>(best_idx, best_has, gtl, lab, mgidx, N, Gn, Bn);
    loss_kernel<<<dim3((N + 255) / 256, Bn), dim3(256), 0, stream>>>(logits, breg, anchors, gtb,
                                                                     lab, mgidx, accum, N, Gn, Cc);
    fin_kernel<<<dim3(1), dim3(1), 0, stream>>>(accum, out, Bn);
}

// Round 4
// 123.690 us; speedup vs baseline: 2.8327x; 1.1212x over previous
//
#include <hip/hip_runtime.h>
#include <math.h>

#define DEG2RAD_F 0.017453292519943295f
#define GATE_ITERS 8

__device__ __forceinline__ float sl1(float d) {
    return (d < 1.0f) ? (0.5f * d * d) : (d - 0.5f);
}

__device__ __forceinline__ float remf180(float x) {
    float r = fmodf(x, 180.0f);
    if (r < 0.0f) r += 180.0f;
    return r;
}

__device__ __forceinline__ float softplusf(float x) {
    if (x > 0.0f) return x + log1pf(expf(-x));
    return log1pf(expf(x));
}

__device__ __forceinline__ void box_corners(float cx, float cy, float w, float h, float t,
                                            float* X, float* Y) {
    float r = t * DEG2RAD_F;
    float c = cosf(r), s = sinf(r);
    const float sx[4] = {-0.5f, 0.5f, 0.5f, -0.5f};
    const float sy[4] = {-0.5f, -0.5f, 0.5f, 0.5f};
#pragma unroll
    for (int i = 0; i < 4; i++) {
        float lx = w * sx[i], ly = h * sy[i];
        X[i] = cx + lx * c - ly * s;
        Y[i] = cy + lx * s + ly * c;
    }
}

// Exact quad-quad intersection area, register-resident (constant indices only).
// Sort = Batcher odd-even merge network for n=32 pruned to 24 wires
// (pruning is valid for standard comparator networks with +inf padding).
// Non-stable is OK: equal keys only arise from coincident points.
__device__ __forceinline__ float quad_inter_area(const float* p1x, const float* p1y,
                                                 const float* p2x, const float* p2y) {
    float X[24], Y[24];
    bool M[24];

#pragma unroll
    for (int i = 0; i < 4; i++) {
        X[i] = p1x[i];
        Y[i] = p1y[i];
        bool ins = true;
#pragma unroll
        for (int k = 0; k < 4; k++) {
            int k2 = (k + 1) & 3;
            float ex = p2x[k2] - p2x[k], ey = p2y[k2] - p2y[k];
            float dx = p1x[i] - p2x[k], dy = p1y[i] - p2y[k];
            ins = ins && (ex * dy - ey * dx >= -1e-6f);
        }
        M[i] = ins;
    }
#pragma unroll
    for (int i = 0; i < 4; i++) {
        X[4 + i] = p2x[i];
        Y[4 + i] = p2y[i];
        bool ins = true;
#pragma unroll
        for (int k = 0; k < 4; k++) {
            int k2 = (k + 1) & 3;
            float ex = p1x[k2] - p1x[k], ey = p1y[k2] - p1y[k];
            float dx = p2x[i] - p1x[k], dy = p2y[i] - p1y[k];
            ins = ins && (ex * dy - ey * dx >= -1e-6f);
        }
        M[4 + i] = ins;
    }
#pragma unroll
    for (int i = 0; i < 4; i++) {
        int i2 = (i + 1) & 3;
        float ax = p1x[i], ay = p1y[i];
        float rx = p1x[i2] - ax, ry = p1y[i2] - ay;
#pragma unroll
        for (int j = 0; j < 4; j++) {
            int j2 = (j + 1) & 3;
            float cx = p2x[j], cy = p2y[j];
            float ux = p2x[j2] - cx, uy = p2y[j2] - cy;
            float qx = cx - ax, qy = cy - ay;
            float den = rx * uy - ry * ux;
            bool dok = fabsf(den) > 1e-10f;
            float safe = dok ? den : 1.0f;
            float t = (qx * uy - qy * ux) / safe;
            float s = (qx * ry - qy * rx) / safe;
            int idx = 8 + i * 4 + j;
            X[idx] = ax + t * rx;
            Y[idx] = ay + t * ry;
            M[idx] = dok && (t >= 0.0f) && (t <= 1.0f) && (s >= 0.0f) && (s <= 1.0f);
        }
    }

    int n = 0;
    float sx = 0.0f, sy = 0.0f;
#pragma unroll
    for (int i = 0; i < 24; i++) {
        n += M[i] ? 1 : 0;
        sx += M[i] ? X[i] : 0.0f;
        sy += M[i] ? Y[i] : 0.0f;
    }
    float denom = (float)(n > 1 ? n : 1);
    float cenx = sx / denom, ceny = sy / denom;

    bool found = false;
    float rfx = X[0], rfy = Y[0];
#pragma unroll
    for (int i = 0; i < 24; i++) {
        bool take = M[i] && !found;
        rfx = take ? X[i] : rfx;
        rfy = take ? Y[i] : rfy;
        found = found || M[i];
    }

    float K[24];
#pragma unroll
    for (int i = 0; i < 24; i++) {
        float xx = M[i] ? X[i] : rfx;
        float yy = M[i] ? Y[i] : rfy;
        X[i] = xx;
        Y[i] = yy;
        float dx = xx - cenx, dy = yy - ceny;
        float ad = fabsf(dx) + fabsf(dy);
        float pg = dy / ad;
        float k = (dx >= 0.0f) ? pg : ((dy >= 0.0f) ? 2.0f - pg : -2.0f - pg);
        K[i] = (ad > 0.0f) ? k : 0.0f;
    }

    auto cswap = [&](int a, int b2) {
        bool sw = K[a] > K[b2];
        float tk = K[a], tx = X[a], ty = Y[a];
        K[a] = sw ? K[b2] : K[a];
        X[a] = sw ? X[b2] : X[a];
        Y[a] = sw ? Y[b2] : Y[a];
        K[b2] = sw ? tk : K[b2];
        X[b2] = sw ? tx : X[b2];
        Y[b2] = sw ? ty : Y[b2];
    };

    // Batcher odd-even merge sort, n=32, comparators with a wire >= 24 pruned.
#pragma unroll
    for (int p = 1; p < 32; p <<= 1) {
#pragma unroll
        for (int k = p; k >= 1; k >>= 1) {
#pragma unroll
            for (int j = (k == p ? 0 : k); j + k < 32; j += 2 * k) {
#pragma unroll
                for (int i = 0; i < k; i++) {
                    if (i + j + k < 32 && ((i + j) / (2 * p) == (i + j + k) / (2 * p))) {
                        if (i + j + k < 24) cswap(i + j, i + j + k);
                    }
                }
            }
        }
    }

    float a2 = 0.0f;
#pragma unroll
    for (int i = 0; i < 24; i++) {
        int j = (i + 1) % 24;
        a2 += X[i] * Y[j] - X[j] * Y[i];
    }
    return (n >= 3) ? 0.5f * fabsf(a2) : 0.0f;
}

// Gate pass with block-level compaction: 8 pairs/thread grid-stride,
// LDS prefix scan, ONE atomicAdd per block.
__global__ void gate_kernel(const float* __restrict__ anchors, const float* __restrict__ gtb,
                            float* __restrict__ iou, int* __restrict__ counter,
                            int* __restrict__ list, int N, int Gn, int Bn, int total) {
    int tx = threadIdx.x;
    int base = blockIdx.x * blockDim.x + tx;
    int stride = gridDim.x * blockDim.x;

    bool pf[GATE_ITERS];
    int pt[GATE_ITERS];
    int cnt = 0;
#pragma unroll
    for (int it = 0; it < GATE_ITERS; it++) {
        int tid = base + it * stride;
        bool pass = false;
        if (tid < total) {
            int g = tid % Gn;
            int rem = tid / Gn;
            int n = rem % N;
            int b = rem / N;
            const float* A = anchors + n * 5;
            const float* Gt = gtb + (b * Gn + g) * 5;
            float asz = fmaxf(A[2], A[3]), gsz = fmaxf(Gt[2], Gt[3]);
            float dx = A[0] - Gt[0], dy = A[1] - Gt[1];
            iou[tid] = 0.0f;
            pass = sqrtf(dx * dx + dy * dy) < 0.7f * (asz + gsz);
        }
        pf[it] = pass;
        pt[it] = tid;
        cnt += pass ? 1 : 0;
    }

    __shared__ int sc[256];
    __shared__ int sbase;
    sc[tx] = cnt;
    __syncthreads();
    for (int d = 1; d < 256; d <<= 1) {
        int v = (tx >= d) ? sc[tx - d] : 0;
        __syncthreads();
        sc[tx] += v;
        __syncthreads();
    }
    if (tx == 255) sbase = atomicAdd(counter, sc[255]);
    __syncthreads();

    int off = sbase + sc[tx] - cnt;
#pragma unroll
    for (int it = 0; it < GATE_ITERS; it++) {
        if (pf[it]) list[off++] = pt[it];
    }
}

// Heavy pass: dense waves over compacted candidates. Block=64 for fine-grain
// CU load balance (~650 blocks over 256 CUs instead of 164 fat blocks).
__global__ void heavy_kernel(const float* __restrict__ anchors, const float* __restrict__ gtb,
                             const int* __restrict__ counter, const int* __restrict__ list,
                             float* __restrict__ iou, int N, int Gn) {
    int i = blockIdx.x * blockDim.x + threadIdx.x;
    if (i >= *counter) return;
    int tid = list[i];
    int g = tid % Gn;
    int rem = tid / Gn;
    int n = rem % N;
    int b = rem / N;

    const float* A = anchors + n * 5;
    const float* Gt = gtb + (b * Gn + g) * 5;
    float aw = A[2], ah = A[3];
    float gw = Gt[2], gh = Gt[3];

    float p1x[4], p1y[4], p2x[4], p2y[4];
    box_corners(A[0], A[1], aw, ah, A[4], p1x, p1y);
    box_corners(Gt[0], Gt[1], gw, gh, Gt[4], p2x, p2y);
    float inter = quad_inter_area(p1x, p1y, p2x, p2y);
    iou[tid] = inter / (aw * ah + gw * gh - inter + 1e-8f);
}

// Fused row-argmax (per anchor) + col-argmax (per gt).
__global__ void rowcol_kernel(const float* __restrict__ iou, const int* __restrict__ gtl,
                              int* __restrict__ lab, int* __restrict__ mgidx,
                              int* __restrict__ best_idx, int* __restrict__ best_has,
                              int N, int Gn, int Bn) {
    __shared__ float sv[256];
    __shared__ int si[256];
    int nRow = (Bn * N + 255) / 256;
    if ((int)blockIdx.x < nRow) {
        int tid = blockIdx.x * 256 + threadIdx.x;
        if (tid >= Bn * N) return;
        int b = tid / N;
        const float* row = iou + (size_t)tid * Gn;
        float mx = row[0];
        int mi = 0;
        for (int g = 1; g < Gn; g++) {
            float v = row[g];
            if (v > mx) { mx = v; mi = g; }
        }
        int l, mg = -1;
        if (mx >= 0.5f) {
            l = gtl[b * Gn + mi] + 1;
            mg = mi;
        } else if (mx < 0.4f) {
            l = 0;
        } else {
            l = -1;
        }
        lab[tid] = l;
        mgidx[tid] = mg;
    } else {
        int id = blockIdx.x - nRow;
        int g = id % Gn;
        int b = id / Gn;
        float mx = -1.0f;
        int mi = 0x7FFFFFFF;
        for (int n = threadIdx.x; n < N; n += 256) {
            float v = iou[((size_t)b * N + n) * Gn + g];
            if (v > mx) { mx = v; mi = n; }
        }
        sv[threadIdx.x] = mx;
        si[threadIdx.x] = mi;
        __syncthreads();
        for (int s = 128; s > 0; s >>= 1) {
            if ((int)threadIdx.x < s) {
                float v2 = sv[threadIdx.x + s];
                int i2 = si[threadIdx.x + s];
                if (v2 > sv[threadIdx.x] ||
                    (v2 == sv[threadIdx.x] && i2 < si[threadIdx.x])) {
                    sv[threadIdx.x] = v2;
                    si[threadIdx.x] = i2;
                }
            }
            __syncthreads();
        }
        if (threadIdx.x == 0) {
            best_idx[b * Gn + g] = si[0];
            best_has[b * Gn + g] = (sv[0] > 0.0f) ? 1 : 0;
        }
    }
}

// Fused: per-anchor force-match emulation + focal + smooth-L1 + block reduce
// + per-image atomics + last-block finalize (replaces force/loss/fin kernels).
// Per-anchor force emulation is exact: the reference's sequential-j loop only
// affects anchor bi via (has_j && best_j==bi && cur!=l_j), which each thread
// replays locally in j order.
__global__ void loss_kernel(const float* __restrict__ logits, const float* __restrict__ breg,
                            const float* __restrict__ anchors, const float* __restrict__ gtb,
                            const int* __restrict__ gtl,
                            const int* __restrict__ lab, const int* __restrict__ mgidx,
                            const int* __restrict__ best_idx, const int* __restrict__ best_has,
                            float* __restrict__ accum, unsigned int* __restrict__ done,
                            float* __restrict__ out, int N, int Gn, int Cc, int Bn) {
    int b = blockIdx.y;
    int n = blockIdx.x * blockDim.x + threadIdx.x;
    float cl = 0.0f, rl = 0.0f, npos = 0.0f;
    if (n < N) {
        int cur = lab[b * N + n];
        int mg = mgidx[b * N + n];
        // replay force-match for this anchor
        for (int j = 0; j < Gn; j++) {
            if (best_has[b * Gn + j] && best_idx[b * Gn + j] == n) {
                int lj = gtl[b * Gn + j] + 1;
                if (cur != lj) { cur = lj; mg = j; }
            }
        }
        if (cur >= 0) {
            const float* lg = logits + ((size_t)b * N + n) * Cc;
            int tc = cur - 1;
            for (int c = 0; c < Cc; c++) {
                float x = lg[c];
                float fl;
                if (cur > 0 && c == tc) {
                    float omp = 1.0f / (1.0f + expf(x));
                    fl = 0.25f * omp * omp * softplusf(-x);
                } else {
                    float p = 1.0f / (1.0f + expf(-x));
                    fl = 0.75f * p * p * softplusf(x);
                }
                cl += fl;
            }
        }
        if (cur > 0) {
            npos = 1.0f;
            const float* A = anchors + n * 5;
            const float* Gt = gtb + ((size_t)b * Gn + mg) * 5;
            float ax = A[0], ay = A[1], aw = A[2], ah = A[3], at = A[4];
            float d0 = (Gt[0] - ax) / aw;
            float d1 = (Gt[1] - ay) / ah;
            float d2 = logf(Gt[2] / aw);
            float d3 = logf(Gt[3] / ah);
            float dth = remf180(Gt[4] - at + 90.0f) - 90.0f;
            const float* br = breg + ((size_t)b * N + n) * 5;
            float s4 = sl1(fabsf(br[0] - d0)) + sl1(fabsf(br[1] - d1)) +
                       sl1(fabsf(br[2] - d2)) + sl1(fabsf(br[3] - d3));
            float da = fabsf(remf180(br[4] - dth + 90.0f) - 90.0f);
            rl = s4 + sl1(da);
        }
    }
    __shared__ float s0[256], s1[256], s2[256];
    int tx = threadIdx.x;
    s0[tx] = cl; s1[tx] = rl; s2[tx] = npos;
    __syncthreads();
    for (int s = 128; s > 0; s >>= 1) {
        if (tx < s) {
            s0[tx] += s0[tx + s];
            s1[tx] += s1[tx + s];
            s2[tx] += s2[tx + s];
        }
        __syncthreads();
    }
    if (tx == 0) {
        atomicAdd(&accum[b * 3 + 0], s0[0]);
        atomicAdd(&accum[b * 3 + 1], s1[0]);
        atomicAdd(&accum[b * 3 + 2], s2[0]);
        __threadfence();
        unsigned int prev = atomicAdd(done, 1u);
        if (prev == gridDim.x * gridDim.y - 1u) {
            __threadfence();
            volatile float* va = (volatile float*)accum;
            float cm = 0.0f, rm = 0.0f;
            for (int bb = 0; bb < Bn; bb++) {
                float np = fmaxf(va[bb * 3 + 2], 1.0f);
                cm += va[bb * 3 + 0] / np;
                rm += va[bb * 3 + 1] / np;
            }
            cm /= (float)Bn;
            rm /= (float)Bn;
            out[0] = cm + rm;
            out[1] = cm;
            out[2] = rm;
        }
    }
}

extern "C" void kernel_launch(void* const* d_in, const int* in_sizes, int n_in,
                              void* d_out, int out_size, void* d_ws, size_t ws_size,
                              hipStream_t stream) {
    const float* logits  = (const float*)d_in[0];
    const float* breg    = (const float*)d_in[1];
    const float* anchors = (const float*)d_in[2];
    const float* gtb     = (const float*)d_in[3];
    const int*   gtl     = (const int*)d_in[4];

    int N  = in_sizes[2] / 5;           // anchors: (N,5)
    int Bn = in_sizes[1] / (N * 5);     // box_regression: (B,N,5)
    int Gn = in_sizes[4] / Bn;          // gt_labels: (B,G)
    int Cc = in_sizes[0] / (Bn * N);    // cls_logits: (B,N,C)

    float* out = (float*)d_out;

    char* w = (char*)d_ws;
    float* iou = (float*)w;       w += sizeof(float) * (size_t)Bn * N * Gn;
    int* list = (int*)w;          w += sizeof(int) * (size_t)Bn * N * Gn;
    int* lab = (int*)w;           w += sizeof(int) * (size_t)Bn * N;
    int* mgidx = (int*)w;         w += sizeof(int) * (size_t)Bn * N;
    int* best_idx = (int*)w;      w += sizeof(int) * Bn * Gn;
    int* best_has = (int*)w;      w += sizeof(int) * Bn * Gn;
    // contiguous zero-init region: counter, done, accum
    int* counter = (int*)w;       w += sizeof(int);
    unsigned int* done = (unsigned int*)w; w += sizeof(unsigned int);
    float* accum = (float*)w;     w += sizeof(float) * 3 * Bn;

    hipMemsetAsync(counter, 0, sizeof(int) + sizeof(unsigned int) + sizeof(float) * 3 * Bn,
                   stream);

    int total = Bn * N * Gn;
    int nGateBlocks = (total + 256 * GATE_ITERS - 1) / (256 * GATE_ITERS);
    gate_kernel<<<dim3(nGateBlocks), dim3(256), 0, stream>>>(anchors, gtb, iou, counter, list,
                                                             N, Gn, Bn, total);
    heavy_kernel<<<dim3((total + 63) / 64), dim3(64), 0, stream>>>(anchors, gtb, counter, list,
                                                                   iou, N, Gn);
    int nRow = (Bn * N + 255) / 256;
    rowcol_kernel<<<dim3(nRow + Bn * Gn), dim3(256), 0, stream>>>(iou, gtl, lab, mgidx,
                                                                  best_idx, best_has, N, Gn, Bn);
    loss_kernel<<<dim3((N + 255) / 256, Bn), dim3(256), 0, stream>>>(
        logits, breg, anchors, gtb, gtl, lab, mgidx, best_idx, best_has,
        accum, done, out, N, Gn, Cc, Bn);
}

// Round 5
// 108.499 us; speedup vs baseline: 3.2293x; 1.1400x over previous
//
#include <hip/hip_runtime.h>
#include <math.h>

#define DEG2RAD_F 0.017453292519943295f
#define ANCH 64   // anchors per fused block

__device__ __forceinline__ float sl1(float d) {
    return (d < 1.0f) ? (0.5f * d * d) : (d - 0.5f);
}

__device__ __forceinline__ float remf180(float x) {
    float r = fmodf(x, 180.0f);
    if (r < 0.0f) r += 180.0f;
    return r;
}

__device__ __forceinline__ float softplusf(float x) {
    if (x > 0.0f) return x + log1pf(expf(-x));
    return log1pf(expf(x));
}

__device__ __forceinline__ void box_corners(float cx, float cy, float w, float h, float t,
                                            float* X, float* Y) {
    float r = t * DEG2RAD_F;
    float c = cosf(r), s = sinf(r);
    const float sx[4] = {-0.5f, 0.5f, 0.5f, -0.5f};
    const float sy[4] = {-0.5f, -0.5f, 0.5f, 0.5f};
#pragma unroll
    for (int i = 0; i < 4; i++) {
        float lx = w * sx[i], ly = h * sy[i];
        X[i] = cx + lx * c - ly * s;
        Y[i] = cy + lx * s + ly * c;
    }
}

// Exact quad-quad intersection area, register-resident (constant indices only).
// Sort = Batcher odd-even merge network (n=32 pruned to 24 wires). Validated
// absmax 0.0 in rounds 2-4.
__device__ __forceinline__ float quad_inter_area(const float* p1x, const float* p1y,
                                                 const float* p2x, const float* p2y) {
    float X[24], Y[24];
    bool M[24];

#pragma unroll
    for (int i = 0; i < 4; i++) {
        X[i] = p1x[i];
        Y[i] = p1y[i];
        bool ins = true;
#pragma unroll
        for (int k = 0; k < 4; k++) {
            int k2 = (k + 1) & 3;
            float ex = p2x[k2] - p2x[k], ey = p2y[k2] - p2y[k];
            float dx = p1x[i] - p2x[k], dy = p1y[i] - p2y[k];
            ins = ins && (ex * dy - ey * dx >= -1e-6f);
        }
        M[i] = ins;
    }
#pragma unroll
    for (int i = 0; i < 4; i++) {
        X[4 + i] = p2x[i];
        Y[4 + i] = p2y[i];
        bool ins = true;
#pragma unroll
        for (int k = 0; k < 4; k++) {
            int k2 = (k + 1) & 3;
            float ex = p1x[k2] - p1x[k], ey = p1y[k2] - p1y[k];
            float dx = p2x[i] - p1x[k], dy = p2y[i] - p1y[k];
            ins = ins && (ex * dy - ey * dx >= -1e-6f);
        }
        M[4 + i] = ins;
    }
#pragma unroll
    for (int i = 0; i < 4; i++) {
        int i2 = (i + 1) & 3;
        float ax = p1x[i], ay = p1y[i];
        float rx = p1x[i2] - ax, ry = p1y[i2] - ay;
#pragma unroll
        for (int j = 0; j < 4; j++) {
            int j2 = (j + 1) & 3;
            float cx = p2x[j], cy = p2y[j];
            float ux = p2x[j2] - cx, uy = p2y[j2] - cy;
            float qx = cx - ax, qy = cy - ay;
            float den = rx * uy - ry * ux;
            bool dok = fabsf(den) > 1e-10f;
            float safe = dok ? den : 1.0f;
            float t = (qx * uy - qy * ux) / safe;
            float s = (qx * ry - qy * rx) / safe;
            int idx = 8 + i * 4 + j;
            X[idx] = ax + t * rx;
            Y[idx] = ay + t * ry;
            M[idx] = dok && (t >= 0.0f) && (t <= 1.0f) && (s >= 0.0f) && (s <= 1.0f);
        }
    }

    int n = 0;
    float sx = 0.0f, sy = 0.0f;
#pragma unroll
    for (int i = 0; i < 24; i++) {
        n += M[i] ? 1 : 0;
        sx += M[i] ? X[i] : 0.0f;
        sy += M[i] ? Y[i] : 0.0f;
    }
    float denom = (float)(n > 1 ? n : 1);
    float cenx = sx / denom, ceny = sy / denom;

    bool found = false;
    float rfx = X[0], rfy = Y[0];
#pragma unroll
    for (int i = 0; i < 24; i++) {
        bool take = M[i] && !found;
        rfx = take ? X[i] : rfx;
        rfy = take ? Y[i] : rfy;
        found = found || M[i];
    }

    float K[24];
#pragma unroll
    for (int i = 0; i < 24; i++) {
        float xx = M[i] ? X[i] : rfx;
        float yy = M[i] ? Y[i] : rfy;
        X[i] = xx;
        Y[i] = yy;
        float dx = xx - cenx, dy = yy - ceny;
        float ad = fabsf(dx) + fabsf(dy);
        float pg = dy / ad;
        float k = (dx >= 0.0f) ? pg : ((dy >= 0.0f) ? 2.0f - pg : -2.0f - pg);
        K[i] = (ad > 0.0f) ? k : 0.0f;
    }

    auto cswap = [&](int a, int b2) {
        bool sw = K[a] > K[b2];
        float tk = K[a], tx = X[a], ty = Y[a];
        K[a] = sw ? K[b2] : K[a];
        X[a] = sw ? X[b2] : X[a];
        Y[a] = sw ? Y[b2] : Y[a];
        K[b2] = sw ? tk : K[b2];
        X[b2] = sw ? tx : X[b2];
        Y[b2] = sw ? ty : Y[b2];
    };

#pragma unroll
    for (int p = 1; p < 32; p <<= 1) {
#pragma unroll
        for (int k = p; k >= 1; k >>= 1) {
#pragma unroll
            for (int j = (k == p ? 0 : k); j + k < 32; j += 2 * k) {
#pragma unroll
                for (int i = 0; i < k; i++) {
                    if (i + j + k < 32 && ((i + j) / (2 * p) == (i + j + k) / (2 * p))) {
                        if (i + j + k < 24) cswap(i + j, i + j + k);
                    }
                }
            }
        }
    }

    float a2 = 0.0f;
#pragma unroll
    for (int i = 0; i < 24; i++) {
        int j = (i + 1) % 24;
        a2 += X[i] * Y[j] - X[j] * Y[i];
    }
    return (n >= 3) ? 0.5f * fabsf(a2) : 0.0f;
}

// K1: per block = 64 anchors x Gn pairs. Gate -> LDS compact -> heavy IoU into
// LDS tile (padded +1: 2-way bank alias = free) -> row argmax (lab/mgidx) +
// 64-lane shfl col-max partials. IoU never touches global memory.
// Block 0 also zeroes done+accum (read by K2 after kernel boundary).
__global__ void fused_kernel(const float* __restrict__ anchors, const float* __restrict__ gtb,
                             const int* __restrict__ gtl,
                             int* __restrict__ lab, int* __restrict__ mgidx,
                             unsigned long long* __restrict__ partial,
                             unsigned int* __restrict__ zero_region,
                             int N, int Gn, int Bn, int NBI) {
    __shared__ int slist[ANCH * 16];
    __shared__ int scount;
    __shared__ float tile[ANCH][17];

    int tx = threadIdx.x;
    if (blockIdx.x == 0 && tx < 8) zero_region[tx] = 0u;  // done + accum[6] + pad

    for (int i = tx; i < ANCH * 17; i += 256) ((float*)tile)[i] = 0.0f;
    if (tx == 0) scount = 0;
    __syncthreads();

    int b = blockIdx.x / NBI;
    int a0 = (blockIdx.x - b * NBI) * ANCH;
    int npairs = ANCH * Gn;

    // gate phase
    for (int p = tx; p < npairs; p += 256) {
        int a = p / Gn, g = p - a * Gn;
        int n = a0 + a;
        if (n < N) {
            const float* A = anchors + n * 5;
            const float* Gt = gtb + (b * Gn + g) * 5;
            float asz = fmaxf(A[2], A[3]), gsz = fmaxf(Gt[2], Gt[3]);
            float dx = A[0] - Gt[0], dy = A[1] - Gt[1];
            if (sqrtf(dx * dx + dy * dy) < 0.7f * (asz + gsz)) {
                int q = atomicAdd(&scount, 1);
                slist[q] = p;
            }
        }
    }
    __syncthreads();

    // heavy phase over compacted local list
    int cnt = scount;
    for (int i = tx; i < cnt; i += 256) {
        int p = slist[i];
        int a = p / Gn, g = p - a * Gn;
        int n = a0 + a;
        const float* A = anchors + n * 5;
        const float* Gt = gtb + (b * Gn + g) * 5;
        float aw = A[2], ah = A[3], gw = Gt[2], gh = Gt[3];
        float p1x[4], p1y[4], p2x[4], p2y[4];
        box_corners(A[0], A[1], aw, ah, A[4], p1x, p1y);
        box_corners(Gt[0], Gt[1], gw, gh, Gt[4], p2x, p2y);
        float inter = quad_inter_area(p1x, p1y, p2x, p2y);
        tile[a][g] = inter / (aw * ah + gw * gh - inter + 1e-8f);
    }
    __syncthreads();

    // wave 0: row argmax + col partials
    if (tx < ANCH) {
        int a = tx;
        int n = a0 + a;
        if (n < N) {
            float mx = tile[a][0];
            int mi = 0;
            for (int g = 1; g < Gn; g++) {
                float v = tile[a][g];
                if (v > mx) { mx = v; mi = g; }
            }
            int l, mg = -1;
            if (mx >= 0.5f) {
                l = gtl[b * Gn + mi] + 1;
                mg = mi;
            } else if (mx < 0.4f) {
                l = 0;
            } else {
                l = -1;
            }
            lab[b * N + n] = l;
            mgidx[b * N + n] = mg;
        }
        // packed col max: (iou_bits << 32) | (~n) -> max == first-argmax
        for (int g = 0; g < Gn; g++) {
            float v = (n < N) ? tile[a][g] : 0.0f;
            unsigned long long pk =
                ((unsigned long long)__float_as_uint(v) << 32) |
                (unsigned long long)(0xFFFFFFFFu - (unsigned)n);
            for (int off = 32; off > 0; off >>= 1) {
                unsigned long long o = __shfl_down(pk, off, 64);
                pk = (o > pk) ? o : pk;
            }
            if (tx == 0) partial[(size_t)blockIdx.x * 16 + g] = pk;
        }
    }
}

// K2: reduce col partials -> best per gt, force-replay + focal + smooth-L1 +
// block reduce + per-image atomics + last-block finalize.
__global__ void loss_kernel(const float* __restrict__ logits, const float* __restrict__ breg,
                            const float* __restrict__ anchors, const float* __restrict__ gtb,
                            const int* __restrict__ gtl,
                            const int* __restrict__ lab, const int* __restrict__ mgidx,
                            const unsigned long long* __restrict__ partial,
                            float* __restrict__ accum, unsigned int* __restrict__ done,
                            float* __restrict__ out, int N, int Gn, int Cc, int Bn, int NBI) {
    int b = blockIdx.y;
    int tx = threadIdx.x;

    __shared__ unsigned long long sseg[16][17];
    __shared__ int sh_has[16];
    __shared__ int sh_idx[16];
    __shared__ int sh_lab[16];

    // reduce NBI partials per g: thread (g = tx&15, seg = tx>>4)
    {
        int g = tx & 15, seg = tx >> 4;
        unsigned long long m = 0ull;
        if (g < Gn) {
            for (int e = seg; e < NBI; e += 16) {
                unsigned long long pk = partial[(size_t)(b * NBI + e) * 16 + g];
                m = (pk > m) ? pk : m;
            }
        }
        sseg[g][seg] = m;
    }
    __syncthreads();
    if (tx < Gn) {
        unsigned long long m = 0ull;
        for (int s2 = 0; s2 < 16; s2++) {
            unsigned long long pk = sseg[tx][s2];
            m = (pk > m) ? pk : m;
        }
        sh_has[tx] = (m >> 32) != 0ull;
        sh_idx[tx] = (int)(0xFFFFFFFFu - (unsigned)(m & 0xFFFFFFFFull));
        sh_lab[tx] = gtl[b * Gn + tx] + 1;
    }
    __syncthreads();

    int n = blockIdx.x * blockDim.x + tx;
    float cl = 0.0f, rl = 0.0f, npos = 0.0f;
    if (n < N) {
        int cur = lab[b * N + n];
        int mg = mgidx[b * N + n];
        // exact sequential force-replay for this anchor
        for (int j = 0; j < Gn; j++) {
            if (sh_has[j] && sh_idx[j] == n) {
                int lj = sh_lab[j];
                if (cur != lj) { cur = lj; mg = j; }
            }
        }
        if (cur >= 0) {
            const float* lg = logits + ((size_t)b * N + n) * Cc;
            int tc = cur - 1;
            for (int c = 0; c < Cc; c++) {
                float x = lg[c];
                float fl;
                if (cur > 0 && c == tc) {
                    float omp = 1.0f / (1.0f + expf(x));
                    fl = 0.25f * omp * omp * softplusf(-x);
                } else {
                    float p = 1.0f / (1.0f + expf(-x));
                    fl = 0.75f * p * p * softplusf(x);
                }
                cl += fl;
            }
        }
        if (cur > 0) {
            npos = 1.0f;
            const float* A = anchors + n * 5;
            const float* Gt = gtb + ((size_t)b * Gn + mg) * 5;
            float ax = A[0], ay = A[1], aw = A[2], ah = A[3], at = A[4];
            float d0 = (Gt[0] - ax) / aw;
            float d1 = (Gt[1] - ay) / ah;
            float d2 = logf(Gt[2] / aw);
            float d3 = logf(Gt[3] / ah);
            float dth = remf180(Gt[4] - at + 90.0f) - 90.0f;
            const float* br = breg + ((size_t)b * N + n) * 5;
            float s4 = sl1(fabsf(br[0] - d0)) + sl1(fabsf(br[1] - d1)) +
                       sl1(fabsf(br[2] - d2)) + sl1(fabsf(br[3] - d3));
            float da = fabsf(remf180(br[4] - dth + 90.0f) - 90.0f);
            rl = s4 + sl1(da);
        }
    }

    __shared__ float s0[256], s1[256], s2[256];
    s0[tx] = cl; s1[tx] = rl; s2[tx] = npos;
    __syncthreads();
    for (int s = 128; s > 0; s >>= 1) {
        if (tx < s) {
            s0[tx] += s0[tx + s];
            s1[tx] += s1[tx + s];
            s2[tx] += s2[tx + s];
        }
        __syncthreads();
    }
    if (tx == 0) {
        atomicAdd(&accum[b * 3 + 0], s0[0]);
        atomicAdd(&accum[b * 3 + 1], s1[0]);
        atomicAdd(&accum[b * 3 + 2], s2[0]);
        __threadfence();
        unsigned int prev = atomicAdd(done, 1u);
        if (prev == gridDim.x * gridDim.y - 1u) {
            __threadfence();
            volatile float* va = (volatile float*)accum;
            float cm = 0.0f, rm = 0.0f;
            for (int bb = 0; bb < Bn; bb++) {
                float np = fmaxf(va[bb * 3 + 2], 1.0f);
                cm += va[bb * 3 + 0] / np;
                rm += va[bb * 3 + 1] / np;
            }
            cm /= (float)Bn;
            rm /= (float)Bn;
            out[0] = cm + rm;
            out[1] = cm;
            out[2] = rm;
        }
    }
}

extern "C" void kernel_launch(void* const* d_in, const int* in_sizes, int n_in,
                              void* d_out, int out_size, void* d_ws, size_t ws_size,
                              hipStream_t stream) {
    const float* logits  = (const float*)d_in[0];
    const float* breg    = (const float*)d_in[1];
    const float* anchors = (const float*)d_in[2];
    const float* gtb     = (const float*)d_in[3];
    const int*   gtl     = (const int*)d_in[4];

    int N  = in_sizes[2] / 5;           // anchors: (N,5)
    int Bn = in_sizes[1] / (N * 5);     // box_regression: (B,N,5)
    int Gn = in_sizes[4] / Bn;          // gt_labels: (B,G)
    int Cc = in_sizes[0] / (Bn * N);    // cls_logits: (B,N,C)

    float* out = (float*)d_out;

    int NBI = (N + ANCH - 1) / ANCH;    // blocks per image in K1
    int nBlk = Bn * NBI;

    char* w = (char*)d_ws;
    unsigned long long* partial = (unsigned long long*)w;
    w += sizeof(unsigned long long) * (size_t)nBlk * 16;
    int* lab = (int*)w;    w += sizeof(int) * (size_t)Bn * N;
    int* mgidx = (int*)w;  w += sizeof(int) * (size_t)Bn * N;
    // zero_region: done (1 u32) + accum (6 f32) + pad, zeroed by K1 block 0
    unsigned int* done = (unsigned int*)w;  w += sizeof(unsigned int);
    float* accum = (float*)w;               w += sizeof(float) * 3 * Bn + sizeof(float);

    fused_kernel<<<dim3(nBlk), dim3(256), 0, stream>>>(anchors, gtb, gtl, lab, mgidx,
                                                       partial, done, N, Gn, Bn, NBI);
    loss_kernel<<<dim3((N + 255) / 256, Bn), dim3(256), 0, stream>>>(
        logits, breg, anchors, gtb, gtl, lab, mgidx, partial,
        accum, done, out, N, Gn, Cc, Bn, NBI);
}